// Round 3
// baseline (391.170 us; speedup 1.0000x reference)
//
#include <hip/hip_runtime.h>
#include <math.h>

// ---------------------------------------------------------------------------
// SurfNetwork, pipelined: 512-thread block processes RPB=4 rays. Per ray-iter:
// issue gathers for ray r+1 + x for ray r+2 (kept in VGPRs, in flight across
// the whole compute phase), consume ray r's gathers, sigma + MFMA MLP.
// Weights live in LDS (global loads mid-iter would drain vmcnt prefetch).
// A0 (gather bf16, stride 40) and H1 (hidden, stride 72) share one union
// buffer: every wave's A-frag is read into regs before the s_wmax barrier,
// after which H1 writes may clobber the region.
// ---------------------------------------------------------------------------

#define RPB 4

typedef short bf16x8 __attribute__((ext_vector_type(8)));
typedef float floatx4 __attribute__((ext_vector_type(4)));

__device__ inline unsigned short f2b(float f) {  // fp32 -> bf16 RNE
    union { float f; unsigned u; } v; v.f = f;
    unsigned r = v.u + 0x7FFF + ((v.u >> 16) & 1);
    return (unsigned short)(r >> 16);
}

// ws layout (ushorts): [0,2048) W0geo frags, [2048,6144) W1, [6144,7168) W2
__global__ void build_frags(const float* __restrict__ W0,
                            const float* __restrict__ W1,
                            const float* __restrict__ W2,
                            unsigned short* __restrict__ wsf) {
    int tid = blockIdx.x * blockDim.x + threadIdx.x;
    if (tid >= 7168) return;
    int lane, j, k, n;
    float val;
    if (tid < 2048) {
        int f = tid >> 9, r = tid & 511; lane = r >> 3; j = r & 7;
        k = ((lane >> 4) * 8) + j;
        n = f * 16 + (lane & 15);
        val = (k < 18) ? W0[(16 + k) * 64 + n] : 0.0f;
    } else if (tid < 6144) {
        int e = tid - 2048;
        int f = e >> 9, r = e & 511; lane = r >> 3; j = r & 7;
        int ks = f >> 2, nt = f & 3;
        k = ks * 32 + ((lane >> 4) * 8) + j;
        n = nt * 16 + (lane & 15);
        val = W1[k * 64 + n];
    } else {
        int e = tid - 6144;
        int f = e >> 9, r = e & 511; lane = r >> 3; j = r & 7;
        k = f * 32 + ((lane >> 4) * 8) + j;
        n = lane & 15;
        val = (n < 3) ? W2[k * 3 + n] : 0.0f;
    }
    wsf[tid] = f2b(val);
}

__global__ __launch_bounds__(512, 6) void surf_main(
    const int*   __restrict__ x,     // (B, 128, 6)
    const float* __restrict__ dvec,  // (B, 16)
    const float* __restrict__ gw,    // (TABLE, 4)
    const float* __restrict__ W0,    // (34, 64)  dir rows
    const float* __restrict__ b0v,   // (64)
    const float* __restrict__ b1v,   // (64)
    const float* __restrict__ b2v,   // (3)
    const unsigned short* __restrict__ wsf,
    float* __restrict__ out_sigma,   // (B, 128)
    float* __restrict__ out_color)   // (B, 3)
{
    const int t    = threadIdx.x;
    const int lane = t & 63;
    const int w    = t >> 6;          // wave 0..7 -> M-tile w
    const int l15  = lane & 15;
    const int quad = lane >> 4;

    __shared__ unsigned short UB[128 * 72];   // union: A0 (stride 40) / H (stride 72)
    __shared__ unsigned short WF[7168];       // weight B-frags
    __shared__ float s_sigl[768];
    __shared__ float s_dirW[64];
    __shared__ float s_wmax[2];
    __shared__ float s_cw[128];
    __shared__ float s_part[128];

    const size_t ray0 = (size_t)blockIdx.x * RPB;

    // ---- weight frags -> LDS (once per block) ----
    {
        const unsigned int* src = (const unsigned int*)wsf;
        unsigned int* dst = (unsigned int*)WF;
        #pragma unroll
        for (int i = 0; i < 7; ++i) dst[t + i * 512] = src[t + i * 512];
    }

    // ---- biases (once) ----
    float b1r[4];
    #pragma unroll
    for (int nt = 0; nt < 4; ++nt) b1r[nt] = b1v[nt * 16 + l15];
    const float b2r = (l15 < 3) ? b2v[l15] : 0.0f;

    // ---- dirW = b0 + d[ray] @ W0dir for all RPB rays (outside pipeline) ----
    float dwAll[RPB];
    if (t < 64) {
        #pragma unroll
        for (int r = 0; r < RPB; ++r) {
            float acc = b0v[t];
            const float* db = dvec + (ray0 + r) * 16;
            #pragma unroll
            for (int i = 0; i < 16; ++i) acc = fmaf(db[i], W0[i * 64 + t], acc);
            dwAll[r] = acc;
        }
    }

    // ---- startup: x(ray0) -> gathers(ray0); x(ray1) ----
    const int* xb = x + ray0 * 768;
    int xq0 = xb[t];
    int xq1 = (t < 256) ? xb[512 + t] : 0;
    float4 g0, g1 = make_float4(0.f, 0.f, 0.f, 0.f);
    g0 = *(const float4*)(gw + (size_t)xq0 * 4);
    if (t < 256) g1 = *(const float4*)(gw + (size_t)xq1 * 4);
    {
        const int* xb1 = x + (ray0 + 1) * 768;
        xq0 = xb1[t];
        xq1 = (t < 256) ? xb1[512 + t] : 0;
    }

    #pragma unroll
    for (int r = 0; r < RPB; ++r) {
        const size_t ray = ray0 + r;

        // ---- issue prefetch for ray r+1 (stays in flight through compute) ----
        float4 ng0 = make_float4(0.f, 0.f, 0.f, 0.f);
        float4 ng1 = make_float4(0.f, 0.f, 0.f, 0.f);
        int nx0 = 0, nx1 = 0;
        if (r + 1 < RPB) {
            ng0 = *(const float4*)(gw + (size_t)xq0 * 4);
            if (t < 256) ng1 = *(const float4*)(gw + (size_t)xq1 * 4);
            if (r + 2 < RPB) {
                const int* xb2 = x + (ray + 2) * 768;
                nx0 = xb2[t];
                if (t < 256) nx1 = xb2[512 + t];
            }
        }

        // ---- consume ray r's gathers -> LDS ----
        {
            int e = t, p = e / 6, li = e - p * 6;
            s_sigl[e] = fminf(fmaxf(g0.x, 0.0f), 1.0f);
            unsigned short* a = UB + p * 40 + li * 3;
            a[0] = f2b(g0.y); a[1] = f2b(g0.z); a[2] = f2b(g0.w);
        }
        if (t < 256) {
            int e = 512 + t, p = e / 6, li = e - p * 6;
            s_sigl[e] = fminf(fmaxf(g1.x, 0.0f), 1.0f);
            unsigned short* a = UB + p * 40 + li * 3;
            a[0] = f2b(g1.y); a[1] = f2b(g1.z); a[2] = f2b(g1.w);
        }
        if (t < 128) {  // zero-pad geo cols 18..31 (re-done each ray: H clobbers)
            unsigned short* a = UB + t * 40;
            *(unsigned int*)(a + 18) = 0u;
            *(uint2*)(a + 20) = make_uint2(0u, 0u);
            *(uint2*)(a + 24) = make_uint2(0u, 0u);
            *(uint2*)(a + 28) = make_uint2(0u, 0u);
        }
        if (t < 64) s_dirW[t] = dwAll[r];
        __syncthreads();                         // B1: staging visible

        // ---- sigma product + wave max (threads 0..127) ----
        float sigma0 = 0.0f;
        if (t < 128) {
            float p = 1.0f;
            #pragma unroll
            for (int l = 0; l < 6; ++l) p *= s_sigl[t * 6 + l];
            sigma0 = p + 1e-4f;
            float m = sigma0;
            #pragma unroll
            for (int off = 32; off; off >>= 1) m = fmaxf(m, __shfl_xor(m, off));
            if (lane == 0) s_wmax[w] = m;
        }
        // ---- A-frag read (must complete before H writes clobber the union) ----
        const int row = w * 16 + l15;
        bf16x8 a0 = *(const bf16x8*)(UB + row * 40 + quad * 8);
        __syncthreads();                         // B2: wmax ready + a0 reads drained

        const float maxv = fmaxf(s_wmax[0], s_wmax[1]);
        if (t < 128) {
            float sigma = sigma0 / maxv;
            out_sigma[ray * 128 + t] = sigma;
            float cw;
            if (t == 0) cw = sigma;
            else {
                float pp = 1.0f;
                #pragma unroll
                for (int l = 0; l < 6; ++l) pp *= s_sigl[(t - 1) * 6 + l];
                cw = (1.0f - (pp + 1e-4f) / maxv) * sigma;
            }
            s_cw[t] = cw;
        }

        // ---- layer 0 ----
        floatx4 acc0[4];
        #pragma unroll
        for (int nt = 0; nt < 4; ++nt) {
            bf16x8 bw = *(const bf16x8*)(WF + nt * 512 + lane * 8);
            float dw = s_dirW[nt * 16 + l15];
            acc0[nt] = (floatx4){dw, dw, dw, dw};
            acc0[nt] = __builtin_amdgcn_mfma_f32_16x16x32_bf16(a0, bw, acc0[nt], 0, 0, 0);
        }
        #pragma unroll
        for (int nt = 0; nt < 4; ++nt)
            #pragma unroll
            for (int rr = 0; rr < 4; ++rr)
                UB[(w * 16 + quad * 4 + rr) * 72 + nt * 16 + l15] =
                    f2b(fmaxf(acc0[nt][rr], 0.0f));

        // ---- layer 1 ----
        bf16x8 a1a = *(const bf16x8*)(UB + row * 72 + quad * 8);
        bf16x8 a1b = *(const bf16x8*)(UB + row * 72 + 32 + quad * 8);
        floatx4 acc1[4];
        #pragma unroll
        for (int nt = 0; nt < 4; ++nt) {
            bf16x8 bwa = *(const bf16x8*)(WF + 2048 + nt * 512 + lane * 8);
            bf16x8 bwb = *(const bf16x8*)(WF + 2048 + (4 + nt) * 512 + lane * 8);
            float bb = b1r[nt];
            acc1[nt] = (floatx4){bb, bb, bb, bb};
            acc1[nt] = __builtin_amdgcn_mfma_f32_16x16x32_bf16(a1a, bwa, acc1[nt], 0, 0, 0);
            acc1[nt] = __builtin_amdgcn_mfma_f32_16x16x32_bf16(a1b, bwb, acc1[nt], 0, 0, 0);
        }
        #pragma unroll
        for (int nt = 0; nt < 4; ++nt)
            #pragma unroll
            for (int rr = 0; rr < 4; ++rr)
                UB[(w * 16 + quad * 4 + rr) * 72 + nt * 16 + l15] =
                    f2b(fmaxf(acc1[nt][rr], 0.0f));

        // ---- layer 2 ----
        bf16x8 a2a = *(const bf16x8*)(UB + row * 72 + quad * 8);
        bf16x8 a2b = *(const bf16x8*)(UB + row * 72 + 32 + quad * 8);
        bf16x8 bw2a = *(const bf16x8*)(WF + 6144 + lane * 8);
        bf16x8 bw2b = *(const bf16x8*)(WF + 6656 + lane * 8);
        floatx4 acc2 = (floatx4){b2r, b2r, b2r, b2r};
        acc2 = __builtin_amdgcn_mfma_f32_16x16x32_bf16(a2a, bw2a, acc2, 0, 0, 0);
        acc2 = __builtin_amdgcn_mfma_f32_16x16x32_bf16(a2b, bw2b, acc2, 0, 0, 0);

        __syncthreads();                         // B3: s_cw visible
        float sum = 0.0f;
        #pragma unroll
        for (int rr = 0; rr < 4; ++rr) {
            float col = 1.0f / (1.0f + __expf(-acc2[rr]));
            sum += s_cw[w * 16 + quad * 4 + rr] * col;
        }
        sum += __shfl_xor(sum, 16);
        sum += __shfl_xor(sum, 32);
        if (lane < 16) s_part[w * 16 + lane] = sum;
        __syncthreads();                         // B4: s_part
        if (t < 3) {
            float o = 0.0f;
            #pragma unroll
            for (int ww = 0; ww < 8; ++ww) o += s_part[ww * 16 + t];
            out_color[ray * 3 + t] = o;
        }

        // ---- rotate pipeline registers ----
        g0 = ng0; g1 = ng1; xq0 = nx0; xq1 = nx1;
    }
}

extern "C" void kernel_launch(void* const* d_in, const int* in_sizes, int n_in,
                              void* d_out, int out_size, void* d_ws, size_t ws_size,
                              hipStream_t stream) {
    const int*   x    = (const int*)d_in[0];
    const float* dvec = (const float*)d_in[1];
    const float* gw   = (const float*)d_in[2];
    const float* W0   = (const float*)d_in[3];
    const float* b0   = (const float*)d_in[4];
    const float* W1   = (const float*)d_in[5];
    const float* b1   = (const float*)d_in[6];
    const float* W2   = (const float*)d_in[7];
    const float* b2   = (const float*)d_in[8];

    const int B = in_sizes[1] / 16;                       // d is (B, 16)
    float* out_sigma = (float*)d_out;                     // (B, 128)
    float* out_color = (float*)d_out + (size_t)B * 128;   // (B, 3)
    unsigned short* wsf = (unsigned short*)d_ws;          // 14336 B used

    build_frags<<<14, 512, 0, stream>>>(W0, W1, W2, wsf);
    surf_main<<<B / RPB, 512, 0, stream>>>(x, dvec, gw, W0, b0, b1, b2, wsf,
                                           out_sigma, out_color);
}

// Round 4
// 349.744 us; speedup vs baseline: 1.1184x; 1.1184x over previous
//
#include <hip/hip_runtime.h>
#include <hip/hip_bf16.h>
#include <math.h>

// ---------------------------------------------------------------------------
// SurfNetwork, barrier-free: one ray per WAVE (64 lanes, 2 points/lane).
// 256-thread block = 4 independent rays; ZERO __syncthreads (HIP barriers
// force s_waitcnt vmcnt(0), which killed round-3's pipeline). All reductions
// are wave shuffles; LDS buffers are wave-private (in-order DS pipe + lgkmcnt
// give correctness). Each lane issues 12 gathers -> massive MLP (memory-level
// parallelism); independent waves overlap gather latency with MFMA compute.
// MLP tile-by-tile: 8 M-tiles of 16 points, 14 MFMA per tile (L0 4, L1 8, L2 2).
// Fragment layouts as verified in round 2:
//   A: lane holds A[m=lane&15][k=(lane>>4)*8+j]
//   C: lane reg r holds C[row=(lane>>4)*4+r][col=lane&15]
// ---------------------------------------------------------------------------

typedef short bf16x8 __attribute__((ext_vector_type(8)));
typedef float floatx4 __attribute__((ext_vector_type(4)));

__device__ inline unsigned short f2b(float f) {  // fp32 -> bf16 RNE
    union { float f; unsigned u; } v; v.f = f;
    unsigned r = v.u + 0x7FFF + ((v.u >> 16) & 1);
    return (unsigned short)(r >> 16);
}
__device__ inline unsigned pk2(float a, float b) {  // two fp32 -> packed bf16x2
    return (unsigned)f2b(a) | ((unsigned)f2b(b) << 16);
}

// ws layout (ushorts): [0,2048) W0geo frags, [2048,6144) W1, [6144,7168) W2
__global__ void build_frags(const float* __restrict__ W0,
                            const float* __restrict__ W1,
                            const float* __restrict__ W2,
                            unsigned short* __restrict__ wsf) {
    int tid = blockIdx.x * blockDim.x + threadIdx.x;
    if (tid >= 7168) return;
    int lane, j, k, n;
    float val;
    if (tid < 2048) {
        int f = tid >> 9, r = tid & 511; lane = r >> 3; j = r & 7;
        k = ((lane >> 4) * 8) + j;
        n = f * 16 + (lane & 15);
        val = (k < 18) ? W0[(16 + k) * 64 + n] : 0.0f;
    } else if (tid < 6144) {
        int e = tid - 2048;
        int f = e >> 9, r = e & 511; lane = r >> 3; j = r & 7;
        int ks = f >> 2, nt = f & 3;
        k = ks * 32 + ((lane >> 4) * 8) + j;
        n = nt * 16 + (lane & 15);
        val = W1[k * 64 + n];
    } else {
        int e = tid - 6144;
        int f = e >> 9, r = e & 511; lane = r >> 3; j = r & 7;
        k = f * 32 + ((lane >> 4) * 8) + j;
        n = lane & 15;
        val = (n < 3) ? W2[k * 3 + n] : 0.0f;
    }
    wsf[tid] = f2b(val);
}

__global__ __launch_bounds__(256) void surf_main(
    const int*   __restrict__ x,     // (B, 128, 6)
    const float* __restrict__ dvec,  // (B, 16)
    const float* __restrict__ gw,    // (TABLE, 4)
    const float* __restrict__ W0,    // (34, 64)  dir rows
    const float* __restrict__ b0v,   // (64)
    const float* __restrict__ b1v,   // (64)
    const float* __restrict__ b2v,   // (3)
    const unsigned short* __restrict__ wsf,
    float* __restrict__ out_sigma,   // (B, 128)
    float* __restrict__ out_color)   // (B, 3)
{
    const int t    = threadIdx.x;
    const int lane = t & 63;
    const int w    = t >> 6;          // wave id = ray slot
    const int l15  = lane & 15;
    const int quad = lane >> 4;
    const size_t ray = (size_t)blockIdx.x * 4 + w;

    // wave-private LDS slices — no cross-wave sharing, no barriers anywhere
    __shared__ unsigned short A0[4][128 * 40];  // geo bf16, K pad 32, stride 40
    __shared__ unsigned short HT[4][16 * 72];   // one M-tile of hidden, stride 72
    __shared__ float cwL[4][128];               // compositing weights
    __shared__ float dwL[4][64];                // b0 + d @ W0dir

    unsigned short* A0w = A0[w];
    unsigned short* HTw = HT[w];
    float* cww = cwL[w];
    float* dww = dwL[w];

    // ---- x indices: 48 B/lane contiguous (3 x dwordx4) ----
    const int* xp = x + ray * 768 + lane * 12;
    const int4 xa = *(const int4*)(xp);
    const int4 xb = *(const int4*)(xp + 4);
    const int4 xc = *(const int4*)(xp + 8);

    // ---- 12 gathers per lane, all in flight together ----
    float4 g[12];
    g[0]  = *(const float4*)(gw + (size_t)xa.x * 4);
    g[1]  = *(const float4*)(gw + (size_t)xa.y * 4);
    g[2]  = *(const float4*)(gw + (size_t)xa.z * 4);
    g[3]  = *(const float4*)(gw + (size_t)xa.w * 4);
    g[4]  = *(const float4*)(gw + (size_t)xb.x * 4);
    g[5]  = *(const float4*)(gw + (size_t)xb.y * 4);
    g[6]  = *(const float4*)(gw + (size_t)xb.z * 4);
    g[7]  = *(const float4*)(gw + (size_t)xb.w * 4);
    g[8]  = *(const float4*)(gw + (size_t)xc.x * 4);
    g[9]  = *(const float4*)(gw + (size_t)xc.y * 4);
    g[10] = *(const float4*)(gw + (size_t)xc.z * 4);
    g[11] = *(const float4*)(gw + (size_t)xc.w * 4);

    // ---- dirW (col = lane) ----
    {
        float acc = b0v[lane];
        const float* db = dvec + ray * 16;
        #pragma unroll
        for (int i = 0; i < 16; ++i) acc = fmaf(db[i], W0[i * 64 + lane], acc);
        dww[lane] = acc;
    }

    // ---- stage 2 points: sigma product + packed geo -> A0 (4x b128/point) ----
    float sig0[2];
    #pragma unroll
    for (int p = 0; p < 2; ++p) {
        const float4* gp = g + 6 * p;
        float s = 1.0f;
        #pragma unroll
        for (int l = 0; l < 6; ++l)
            s *= fminf(fmaxf(gp[l].x, 0.0f), 1.0f);
        sig0[p] = s + 1e-4f;
        unsigned u0 = pk2(gp[0].y, gp[0].z);
        unsigned u1 = pk2(gp[0].w, gp[1].y);
        unsigned u2 = pk2(gp[1].z, gp[1].w);
        unsigned u3 = pk2(gp[2].y, gp[2].z);
        unsigned u4 = pk2(gp[2].w, gp[3].y);
        unsigned u5 = pk2(gp[3].z, gp[3].w);
        unsigned u6 = pk2(gp[4].y, gp[4].z);
        unsigned u7 = pk2(gp[4].w, gp[5].y);
        unsigned u8 = pk2(gp[5].z, gp[5].w);
        int4* dst = (int4*)(A0w + (lane * 2 + p) * 40);
        dst[0] = make_int4((int)u0, (int)u1, (int)u2, (int)u3);
        dst[1] = make_int4((int)u4, (int)u5, (int)u6, (int)u7);
        dst[2] = make_int4((int)u8, 0, 0, 0);
        dst[3] = make_int4(0, 0, 0, 0);
    }

    // ---- sigma normalize + compositing weights (all wave-local) ----
    float m = fmaxf(sig0[0], sig0[1]);
    #pragma unroll
    for (int off = 1; off < 64; off <<= 1)
        m = fmaxf(m, __shfl_xor(m, off));
    const float sp0 = sig0[0] / m;
    const float sp1 = sig0[1] / m;
    {
        float2 sv; sv.x = sp0; sv.y = sp1;
        *(float2*)(out_sigma + ray * 128 + lane * 2) = sv;
    }
    const float prev = __shfl_up(sp1, 1);  // sigma of point 2*lane-1
    const float cw0 = (lane == 0) ? sp0 : (1.0f - prev) * sp0;
    const float cw1 = (1.0f - sp0) * sp1;
    {
        float2 cv; cv.x = cw0; cv.y = cw1;
        *(float2*)(cww + lane * 2) = cv;
    }

    // ---- weights/biases (L1/L2-hot; waits hidden by cross-wave overlap) ----
    bf16x8 bw0[4], bw1[8], bw2[2];
    #pragma unroll
    for (int i = 0; i < 4; ++i) bw0[i] = *(const bf16x8*)(wsf + i * 512 + lane * 8);
    #pragma unroll
    for (int i = 0; i < 8; ++i) bw1[i] = *(const bf16x8*)(wsf + 2048 + i * 512 + lane * 8);
    bw2[0] = *(const bf16x8*)(wsf + 6144 + lane * 8);
    bw2[1] = *(const bf16x8*)(wsf + 6656 + lane * 8);
    float b1r[4];
    #pragma unroll
    for (int nt = 0; nt < 4; ++nt) b1r[nt] = b1v[nt * 16 + l15];
    const float b2r = (l15 < 3) ? b2v[l15] : 0.0f;
    float dw4[4];
    #pragma unroll
    for (int nt = 0; nt < 4; ++nt) dw4[nt] = dww[nt * 16 + l15];

    // ---- MLP, one M-tile (16 points) at a time; HT reused (in-order DS) ----
    float csum = 0.0f;
    for (int mt = 0; mt < 8; ++mt) {
        bf16x8 a0 = *(const bf16x8*)(A0w + (mt * 16 + l15) * 40 + quad * 8);

        floatx4 acc0[4];
        #pragma unroll
        for (int nt = 0; nt < 4; ++nt) {
            float dw = dw4[nt];
            acc0[nt] = (floatx4){dw, dw, dw, dw};
            acc0[nt] = __builtin_amdgcn_mfma_f32_16x16x32_bf16(a0, bw0[nt], acc0[nt], 0, 0, 0);
        }
        #pragma unroll
        for (int nt = 0; nt < 4; ++nt)
            #pragma unroll
            for (int r = 0; r < 4; ++r)
                HTw[(quad * 4 + r) * 72 + nt * 16 + l15] = f2b(fmaxf(acc0[nt][r], 0.0f));

        bf16x8 a1a = *(const bf16x8*)(HTw + l15 * 72 + quad * 8);
        bf16x8 a1b = *(const bf16x8*)(HTw + l15 * 72 + 32 + quad * 8);
        floatx4 acc1[4];
        #pragma unroll
        for (int nt = 0; nt < 4; ++nt) {
            float bb = b1r[nt];
            acc1[nt] = (floatx4){bb, bb, bb, bb};
            acc1[nt] = __builtin_amdgcn_mfma_f32_16x16x32_bf16(a1a, bw1[nt],     acc1[nt], 0, 0, 0);
            acc1[nt] = __builtin_amdgcn_mfma_f32_16x16x32_bf16(a1b, bw1[4 + nt], acc1[nt], 0, 0, 0);
        }
        #pragma unroll
        for (int nt = 0; nt < 4; ++nt)
            #pragma unroll
            for (int r = 0; r < 4; ++r)
                HTw[(quad * 4 + r) * 72 + nt * 16 + l15] = f2b(fmaxf(acc1[nt][r], 0.0f));

        bf16x8 a2a = *(const bf16x8*)(HTw + l15 * 72 + quad * 8);
        bf16x8 a2b = *(const bf16x8*)(HTw + l15 * 72 + 32 + quad * 8);
        floatx4 acc2 = (floatx4){b2r, b2r, b2r, b2r};
        acc2 = __builtin_amdgcn_mfma_f32_16x16x32_bf16(a2a, bw2[0], acc2, 0, 0, 0);
        acc2 = __builtin_amdgcn_mfma_f32_16x16x32_bf16(a2b, bw2[1], acc2, 0, 0, 0);

        floatx4 cwq = *(const floatx4*)(cww + mt * 16 + quad * 4);
        #pragma unroll
        for (int r = 0; r < 4; ++r)
            csum += cwq[r] / (1.0f + __expf(-acc2[r]));
    }

    // columns live in l15; fold the 4 quads
    csum += __shfl_xor(csum, 16);
    csum += __shfl_xor(csum, 32);
    if (lane < 3) out_color[ray * 3 + lane] = csum;
}

extern "C" void kernel_launch(void* const* d_in, const int* in_sizes, int n_in,
                              void* d_out, int out_size, void* d_ws, size_t ws_size,
                              hipStream_t stream) {
    const int*   x    = (const int*)d_in[0];
    const float* dvec = (const float*)d_in[1];
    const float* gw   = (const float*)d_in[2];
    const float* W0   = (const float*)d_in[3];
    const float* b0   = (const float*)d_in[4];
    const float* W1   = (const float*)d_in[5];
    const float* b1   = (const float*)d_in[6];
    const float* W2   = (const float*)d_in[7];
    const float* b2   = (const float*)d_in[8];

    const int B = in_sizes[1] / 16;                       // d is (B, 16)
    float* out_sigma = (float*)d_out;                     // (B, 128)
    float* out_color = (float*)d_out + (size_t)B * 128;   // (B, 3)
    unsigned short* wsf = (unsigned short*)d_ws;          // 14336 B used

    build_frags<<<14, 512, 0, stream>>>(W0, W1, W2, wsf);
    surf_main<<<B / 4, 256, 0, stream>>>(x, dvec, gw, W0, b0, b1, b2, wsf,
                                         out_sigma, out_color);
}